// Round 3
// baseline (449.640 us; speedup 1.0000x reference)
//
#include <hip/hip_runtime.h>

#define NN 100000      // nodes
#define NE 1600000     // edges
#define DD 128         // input dim (elements per row)
#define MD 512         // mlp dim = 128*4
#define SEL 16384      // senders count
#define MROWS 32768    // senders + receivers rows
#define NPART 8        // CSR-fill partitions (~XCDs)

typedef __attribute__((ext_vector_type(8))) short bf16x8;
typedef __attribute__((ext_vector_type(4))) float f32x4;

__device__ __forceinline__ unsigned short f2bf(float f) {
  unsigned u = __float_as_uint(f);
  u += 0x7fff + ((u >> 16) & 1);   // round-to-nearest-even
  return (unsigned short)(u >> 16);
}
__device__ __forceinline__ float bflo(unsigned v) { return __uint_as_float(v << 16); }
__device__ __forceinline__ float bfhi(unsigned v) { return __uint_as_float(v & 0xffff0000u); }

// ---- degree histogram over dst ----
__global__ void k_deg(const int* __restrict__ dst, int* __restrict__ deg) {
  int e = blockIdx.x * blockDim.x + threadIdx.x;
  if (e < NE) atomicAdd(&deg[dst[e]], 1);
}

__global__ void k_dinv(const int* __restrict__ deg, float* __restrict__ dinv) {
  int n = blockIdx.x * blockDim.x + threadIdx.x;
  if (n < NN) dinv[n] = rsqrtf(fmaxf((float)deg[n], 1.0f));
}

// ---- exclusive scan of deg -> rowstart (3-kernel) ----
__global__ __launch_bounds__(1024) void k_scan1(const int* __restrict__ deg,
                                                int* __restrict__ excl,
                                                int* __restrict__ part) {
  __shared__ int sm[1024];
  int tid = threadIdx.x;
  int i = blockIdx.x * 1024 + tid;
  int v = (i < NN) ? deg[i] : 0;
  sm[tid] = v;
  __syncthreads();
  for (int o = 1; o < 1024; o <<= 1) {
    int t = (tid >= o) ? sm[tid - o] : 0;
    __syncthreads();
    sm[tid] += t;
    __syncthreads();
  }
  if (i < NN) excl[i] = sm[tid] - v;
  if (tid == 1023) part[blockIdx.x] = sm[1023];
}

__global__ __launch_bounds__(256) void k_scan2(int* __restrict__ part, int nb) {
  __shared__ int sm[256];
  int tid = threadIdx.x;
  int v = (tid < nb) ? part[tid] : 0;
  sm[tid] = v;
  __syncthreads();
  for (int o = 1; o < 256; o <<= 1) {
    int t = (tid >= o) ? sm[tid - o] : 0;
    __syncthreads();
    sm[tid] += t;
    __syncthreads();
  }
  if (tid < nb) part[tid] = sm[tid] - v;
}

__global__ void k_scan3(int* __restrict__ excl, const int* __restrict__ part) {
  int i = blockIdx.x * blockDim.x + threadIdx.x;
  if (i < NN) excl[i] += part[i >> 10];
}

// ---- XCD-partitioned CSR fill: csr[slot] = src (4B entries) ----
// Partition p = blockIdx&7 handles dst in [p*12500, (p+1)*12500): its CSR
// slice (~0.8 MB) stays resident in that XCD's L2 so writes coalesce.
__global__ __launch_bounds__(256) void k_fill(const int* __restrict__ src,
                                              const int* __restrict__ dst,
                                              const int* __restrict__ rowstart,
                                              int* __restrict__ cursor,
                                              int* __restrict__ csr) {
  const int p = blockIdx.x & (NPART - 1);
  const int r = blockIdx.x >> 3;
  const int R = gridDim.x >> 3;
  const int lo = p * (NN / NPART);
  const int hi = lo + (NN / NPART);
  for (int e = r * 256 + threadIdx.x; e < NE; e += R * 256) {
    const int d = dst[e];
    if (d < lo || d >= hi) continue;
    const int pos = atomicAdd(&cursor[d], 1);
    csr[rowstart[d] + pos] = src[e];
  }
}

// ---- mark + compact the nodes needed by the final layer ----
__global__ void k_mark(const int* __restrict__ sl, const int* __restrict__ rl,
                       int* __restrict__ mark) {
  int i = blockIdx.x * blockDim.x + threadIdx.x;
  if (i < SEL) mark[sl[i]] = 1;
  else if (i < 2 * SEL) mark[rl[i - SEL]] = 1;
}

__global__ void k_compact(const int* __restrict__ mark, int* __restrict__ list,
                          int* __restrict__ cnt) {
  int n = blockIdx.x * blockDim.x + threadIdx.x;
  if (n < NN && mark[n]) {
    int p = atomicAdd(cnt, 1);
    list[p] = n;
  }
}

// ---- per-node bf16 aggregation: wave per node, 8 gathers in flight ----
// out[n] = dinv[n] * sum_j dinv[src_j] * x[src_j]
__device__ __forceinline__ void agg_row(int n, int lane,
                                        const int* __restrict__ rowstart,
                                        const int* __restrict__ deg,
                                        const int* __restrict__ csr,
                                        const float* __restrict__ dinv,
                                        const unsigned short* __restrict__ xin,
                                        unsigned short* __restrict__ xout) {
  const int start = rowstart[n];
  const int cnt = deg[n];
  unsigned* orow = (unsigned*)(xout + (size_t)n * DD);
  if (cnt == 0) { orow[lane] = 0u; return; }
  const float wd = dinv[n];
  float ax[8], ay[8];
  #pragma unroll
  for (int u = 0; u < 8; ++u) { ax[u] = 0.f; ay[u] = 0.f; }
  for (int j = 0; j < cnt; j += 8) {
    int idx[8]; float w[8]; unsigned v[8];
    #pragma unroll
    for (int u = 0; u < 8; ++u) {
      const int jj = j + u;
      idx[u] = csr[start + ((jj < cnt) ? jj : (cnt - 1))];
    }
    #pragma unroll
    for (int u = 0; u < 8; ++u)
      w[u] = (j + u < cnt) ? dinv[idx[u]] : 0.f;
    #pragma unroll
    for (int u = 0; u < 8; ++u)
      v[u] = ((const unsigned*)(xin + (size_t)idx[u] * DD))[lane];
    #pragma unroll
    for (int u = 0; u < 8; ++u) {
      ax[u] = fmaf(w[u], bflo(v[u]), ax[u]);
      ay[u] = fmaf(w[u], bfhi(v[u]), ay[u]);
    }
  }
  float rx = ((ax[0] + ax[1]) + (ax[2] + ax[3])) + ((ax[4] + ax[5]) + (ax[6] + ax[7]));
  float ry = ((ay[0] + ay[1]) + (ay[2] + ay[3])) + ((ay[4] + ay[5]) + (ay[6] + ay[7]));
  rx *= wd; ry *= wd;
  orow[lane] = ((unsigned)f2bf(ry) << 16) | (unsigned)f2bf(rx);
}

__global__ __launch_bounds__(256) void k_agg(const int* __restrict__ rowstart,
                                             const int* __restrict__ deg,
                                             const int* __restrict__ csr,
                                             const float* __restrict__ dinv,
                                             const unsigned short* __restrict__ xin,
                                             unsigned short* __restrict__ xout) {
  const int lane = threadIdx.x & 63;
  const int wid = (blockIdx.x * blockDim.x + threadIdx.x) >> 6;
  const int nw = (gridDim.x * blockDim.x) >> 6;
  for (int n = wid; n < NN; n += nw)
    agg_row(n, lane, rowstart, deg, csr, dinv, xin, xout);
}

__global__ __launch_bounds__(256) void k_agg_list(const int* __restrict__ rowstart,
                                                  const int* __restrict__ deg,
                                                  const int* __restrict__ csr,
                                                  const float* __restrict__ dinv,
                                                  const unsigned short* __restrict__ xin,
                                                  unsigned short* __restrict__ xout,
                                                  const int* __restrict__ list,
                                                  const int* __restrict__ lcnt) {
  const int lane = threadIdx.x & 63;
  const int wid = (blockIdx.x * blockDim.x + threadIdx.x) >> 6;
  const int nw = (gridDim.x * blockDim.x) >> 6;
  const int cl = *lcnt;
  for (int i = wid; i < cl; i += nw)
    agg_row(list[i], lane, rowstart, deg, csr, dinv, xin, xout);
}

// ---- gather + l2-normalize selected bf16 rows -> bf16 A-matrix slice ----
__global__ __launch_bounds__(256) void k_gnorm(const int* __restrict__ sl,
                                               const int* __restrict__ rl,
                                               const unsigned short* __restrict__ xin,
                                               unsigned short* __restrict__ Abf,
                                               int colbase) {
  const int lane = threadIdx.x & 63;
  const int row = blockIdx.x * 4 + (threadIdx.x >> 6);
  if (row >= MROWS) return;
  const int node = (row < SEL) ? sl[row] : rl[row - SEL];
  const unsigned v = ((const unsigned*)(xin + (size_t)node * DD))[lane];
  const float x0 = bflo(v), x1 = bfhi(v);
  float ss = fmaf(x0, x0, x1 * x1);
  #pragma unroll
  for (int m = 32; m >= 1; m >>= 1) ss += __shfl_xor(ss, m);
  const float sc = 1.0f / fmaxf(sqrtf(ss), 1e-12f);
  const unsigned short b0 = f2bf(x0 * sc), b1 = f2bf(x1 * sc);
  const unsigned pack = ((unsigned)b1 << 16) | (unsigned)b0;
  *(unsigned*)(Abf + (size_t)row * MD + colbase + lane * 2) = pack;
}

// ---- f32 -> bf16 bulk convert (W and emb) ----
__global__ void k_conv(const float* __restrict__ in, unsigned short* __restrict__ out,
                       int n4) {
  int i = blockIdx.x * blockDim.x + threadIdx.x;
  if (i >= n4) return;
  float4 v = ((const float4*)in)[i];
  ushort4 o;
  o.x = f2bf(v.x); o.y = f2bf(v.y); o.z = f2bf(v.z); o.w = f2bf(v.w);
  ((ushort4*)out)[i] = o;
}

// ---- MFMA GEMM: out[i][j] = sum_k A[i][k]*W[j][k] + bias[j] ----
__global__ __launch_bounds__(256) void k_gemm(const unsigned short* __restrict__ A,
                                              const unsigned short* __restrict__ B,
                                              const float* __restrict__ bias,
                                              float* __restrict__ out) {
  __shared__ unsigned short As[128][40];  // +8 pad breaks bank conflicts
  __shared__ unsigned short Bs[128][40];
  const int t = threadIdx.x;
  const int mt = blockIdx.x >> 2, nt = blockIdx.x & 3;
  const int i0 = mt * 128, j0 = nt * 128;
  const int lane = t & 63, wid = t >> 6;
  const int wr = wid >> 1, wc = wid & 1;    // 2x2 waves, 64x64 each
  const int fr = lane & 15, kg = lane >> 4; // fragment row/col, k-group
  f32x4 acc[4][4] = {};
  for (int k0 = 0; k0 < MD; k0 += 32) {
    #pragma unroll
    for (int rep = 0; rep < 2; ++rep) {
      int id = t + rep * 256;
      int row = id >> 2, seg = id & 3;  // 128 rows x 4 segs of 8 bf16
      float4 va = *(const float4*)(A + (size_t)(i0 + row) * MD + k0 + seg * 8);
      *(float4*)(&As[row][seg * 8]) = va;
      float4 vb = *(const float4*)(B + (size_t)(j0 + row) * MD + k0 + seg * 8);
      *(float4*)(&Bs[row][seg * 8]) = vb;
    }
    __syncthreads();
    bf16x8 af[4], bfr[4];
    #pragma unroll
    for (int m = 0; m < 4; ++m)
      af[m] = *(const bf16x8*)(&As[wr * 64 + m * 16 + fr][kg * 8]);
    #pragma unroll
    for (int n = 0; n < 4; ++n)
      bfr[n] = *(const bf16x8*)(&Bs[wc * 64 + n * 16 + fr][kg * 8]);
    #pragma unroll
    for (int m = 0; m < 4; ++m)
      #pragma unroll
      for (int n = 0; n < 4; ++n)
        acc[m][n] = __builtin_amdgcn_mfma_f32_16x16x32_bf16(af[m], bfr[n], acc[m][n], 0, 0, 0);
    __syncthreads();
  }
  #pragma unroll
  for (int n = 0; n < 4; ++n) {
    int col = j0 + wc * 64 + n * 16 + fr;
    float bv = bias[col];
    #pragma unroll
    for (int m = 0; m < 4; ++m) {
      int r0 = i0 + wr * 64 + m * 16 + kg * 4;
      #pragma unroll
      for (int r = 0; r < 4; ++r)
        out[(size_t)(r0 + r) * MD + col] = acc[m][n][r] + bv;
    }
  }
}

extern "C" void kernel_launch(void* const* d_in, const int* in_sizes, int n_in,
                              void* d_out, int out_size, void* d_ws, size_t ws_size,
                              hipStream_t stream) {
  const float* emb = (const float*)d_in[0];
  const int* ei = (const int*)d_in[1];
  const int* esrc = ei;                     // edge_index[0]
  const int* edst = ei + NE;                // edge_index[1]
  const int* send = (const int*)d_in[2];
  const int* recv = (const int*)d_in[3];
  const float* W = (const float*)d_in[4];
  const float* bias = (const float*)d_in[5];
  float* out = (float*)d_out;

  char* ws = (char*)d_ws;
  size_t off = 0;
  auto take = [&](size_t b) {
    char* p = ws + off;
    off = (off + b + 1023) & ~(size_t)1023;
    return p;
  };
  int* degI = (int*)take((size_t)NN * 4);
  float* dinv = (float*)take((size_t)NN * 4);
  int* rowstart = (int*)take((size_t)NN * 4);
  int* cursor = (int*)take((size_t)NN * 4);
  int* mark = (int*)take((size_t)NN * 4);
  int* list = (int*)take((size_t)MROWS * 4);
  int* lcnt = (int*)take(4);
  int* part = (int*)take(256 * 4);
  int* csr = (int*)take((size_t)NE * 4);
  unsigned short* x0 = (unsigned short*)take((size_t)NN * DD * 2);
  unsigned short* x1 = (unsigned short*)take((size_t)NN * DD * 2);
  unsigned short* x2 = (unsigned short*)take((size_t)NN * DD * 2);
  unsigned short* Abf = (unsigned short*)take((size_t)MROWS * MD * 2);
  unsigned short* Wbf = (unsigned short*)take((size_t)MD * MD * 2);
  (void)ws_size; (void)in_sizes; (void)n_in; (void)out_size;

  hipMemsetAsync(degI, 0, (size_t)NN * 4, stream);
  hipMemsetAsync(cursor, 0, (size_t)NN * 4, stream);
  hipMemsetAsync(mark, 0, (size_t)NN * 4, stream);
  hipMemsetAsync(lcnt, 0, 4, stream);

  k_deg<<<(NE + 255) / 256, 256, 0, stream>>>(edst, degI);
  k_dinv<<<(NN + 255) / 256, 256, 0, stream>>>(degI, dinv);
  const int NB = (NN + 1023) / 1024;
  k_scan1<<<NB, 1024, 0, stream>>>(degI, rowstart, part);
  k_scan2<<<1, 256, 0, stream>>>(part, NB);
  k_scan3<<<(NN + 255) / 256, 256, 0, stream>>>(rowstart, part);
  k_fill<<<2048, 256, 0, stream>>>(esrc, edst, rowstart, cursor, csr);
  k_mark<<<(2 * SEL + 255) / 256, 256, 0, stream>>>(send, recv, mark);
  k_compact<<<(NN + 255) / 256, 256, 0, stream>>>(mark, list, lcnt);
  k_conv<<<(MD * MD / 4 + 255) / 256, 256, 0, stream>>>(W, Wbf, MD * MD / 4);
  k_conv<<<(NN * DD / 4 + 255) / 256, 256, 0, stream>>>(emb, x0, NN * DD / 4);

  // z1 slice from bf16 emb; 2 full layers; masked final layer (reuses x0)
  k_gnorm<<<MROWS / 4, 256, 0, stream>>>(send, recv, x0, Abf, 0);
  k_agg<<<2048, 256, 0, stream>>>(rowstart, degI, csr, dinv, x0, x1);
  k_gnorm<<<MROWS / 4, 256, 0, stream>>>(send, recv, x1, Abf, 128);
  k_agg<<<2048, 256, 0, stream>>>(rowstart, degI, csr, dinv, x1, x2);
  k_gnorm<<<MROWS / 4, 256, 0, stream>>>(send, recv, x2, Abf, 256);
  k_agg_list<<<1024, 256, 0, stream>>>(rowstart, degI, csr, dinv, x2, x0, list, lcnt);
  k_gnorm<<<MROWS / 4, 256, 0, stream>>>(send, recv, x0, Abf, 384);

  k_gemm<<<(MROWS / 128) * (MD / 128), 256, 0, stream>>>(Abf, Wbf, bias, out);
}

// Round 4
// 441.026 us; speedup vs baseline: 1.0195x; 1.0195x over previous
//
#include <hip/hip_runtime.h>

#define NN 100000      // nodes
#define NE 1600000     // edges
#define DD 128         // input dim (elements per row)
#define MD 512         // mlp dim = 128*4
#define SEL 16384      // senders count
#define MROWS 32768    // senders + receivers rows
#define NPART 8        // CSR-fill partitions (~XCDs)

typedef __attribute__((ext_vector_type(8))) short bf16x8;
typedef __attribute__((ext_vector_type(4))) float f32x4;

__device__ __forceinline__ unsigned short f2bf(float f) {
  unsigned u = __float_as_uint(f);
  u += 0x7fff + ((u >> 16) & 1);   // round-to-nearest-even
  return (unsigned short)(u >> 16);
}
__device__ __forceinline__ float bflo(unsigned v) { return __uint_as_float(v << 16); }
__device__ __forceinline__ float bfhi(unsigned v) { return __uint_as_float(v & 0xffff0000u); }

// ---- degree histogram over dst ----
__global__ void k_deg(const int* __restrict__ dst, int* __restrict__ deg) {
  int e = blockIdx.x * blockDim.x + threadIdx.x;
  if (e < NE) atomicAdd(&deg[dst[e]], 1);
}

__global__ void k_dinv(const int* __restrict__ deg, float* __restrict__ dinv) {
  int n = blockIdx.x * blockDim.x + threadIdx.x;
  if (n < NN) dinv[n] = rsqrtf(fmaxf((float)deg[n], 1.0f));
}

// ---- exclusive scan of PADDED degree -> rowstart (3-kernel) ----
// rowstart padded to multiples of 4 so agg can read int4-aligned chunks.
__global__ __launch_bounds__(1024) void k_scan1(const int* __restrict__ deg,
                                                int* __restrict__ excl,
                                                int* __restrict__ part) {
  __shared__ int sm[1024];
  int tid = threadIdx.x;
  int i = blockIdx.x * 1024 + tid;
  int v = (i < NN) ? ((deg[i] + 3) & ~3) : 0;
  sm[tid] = v;
  __syncthreads();
  for (int o = 1; o < 1024; o <<= 1) {
    int t = (tid >= o) ? sm[tid - o] : 0;
    __syncthreads();
    sm[tid] += t;
    __syncthreads();
  }
  if (i < NN) excl[i] = sm[tid] - v;
  if (tid == 1023) part[blockIdx.x] = sm[1023];
}

__global__ __launch_bounds__(256) void k_scan2(int* __restrict__ part, int nb) {
  __shared__ int sm[256];
  int tid = threadIdx.x;
  int v = (tid < nb) ? part[tid] : 0;
  sm[tid] = v;
  __syncthreads();
  for (int o = 1; o < 256; o <<= 1) {
    int t = (tid >= o) ? sm[tid - o] : 0;
    __syncthreads();
    sm[tid] += t;
    __syncthreads();
  }
  if (tid < nb) part[tid] = sm[tid] - v;
}

__global__ void k_scan3(int* __restrict__ excl, const int* __restrict__ part) {
  int i = blockIdx.x * blockDim.x + threadIdx.x;
  if (i < NN) excl[i] += part[i >> 10];
}

// ---- XCD-partitioned CSR fill: csr[slot] = src (4B entries) ----
// Partition p = blockIdx&7 handles dst in [p*12500, (p+1)*12500): its CSR
// slice (~0.9 MB) stays resident in that XCD's L2 so writes coalesce.
__global__ __launch_bounds__(256) void k_fill(const int* __restrict__ src,
                                              const int* __restrict__ dst,
                                              const int* __restrict__ rowstart,
                                              int* __restrict__ cursor,
                                              int* __restrict__ csr) {
  const int p = blockIdx.x & (NPART - 1);
  const int r = blockIdx.x >> 3;
  const int R = gridDim.x >> 3;
  const int lo = p * (NN / NPART);
  const int hi = lo + (NN / NPART);
  for (int e = r * 256 + threadIdx.x; e < NE; e += R * 256) {
    const int d = dst[e];
    if (d < lo || d >= hi) continue;
    const int pos = atomicAdd(&cursor[d], 1);
    csr[rowstart[d] + pos] = src[e];
  }
}

// ---- mark + compact the nodes needed by the final layer ----
__global__ void k_mark(const int* __restrict__ sl, const int* __restrict__ rl,
                       int* __restrict__ mark) {
  int i = blockIdx.x * blockDim.x + threadIdx.x;
  if (i < SEL) mark[sl[i]] = 1;
  else if (i < 2 * SEL) mark[rl[i - SEL]] = 1;
}

__global__ void k_compact(const int* __restrict__ mark, int* __restrict__ list,
                          int* __restrict__ cnt) {
  int n = blockIdx.x * blockDim.x + threadIdx.x;
  if (n < NN && mark[n]) {
    int p = atomicAdd(cnt, 1);
    list[p] = n;
  }
}

// ---- per-node aggregation of u = dinv*x: pure sum, then dinv^2 scale ----
// u_next[d] = dinv[d]^2 * sum_{s in N(d)} u[s]
__device__ __forceinline__ void agg_row(int n, int lane,
                                        const int* __restrict__ rowstart,
                                        const int* __restrict__ deg,
                                        const int* __restrict__ csr,
                                        const float* __restrict__ dinv,
                                        const unsigned short* __restrict__ xin,
                                        unsigned short* __restrict__ xout) {
  const int start = rowstart[n];
  const int cnt = deg[n];
  unsigned* orow = (unsigned*)(xout + (size_t)n * DD);
  if (cnt == 0) { orow[lane] = 0u; return; }
  float ax0 = 0.f, ay0 = 0.f, ax1 = 0.f, ay1 = 0.f;
  float ax2 = 0.f, ay2 = 0.f, ax3 = 0.f, ay3 = 0.f;
  for (int j = 0; j < cnt; j += 4) {
    const int4 e = *(const int4*)(csr + start + j);  // 16B-aligned (padded rows)
    unsigned v0 = ((const unsigned*)(xin + (size_t)e.x * DD))[lane];
    unsigned v1 = ((const unsigned*)(xin + (size_t)e.y * DD))[lane];
    unsigned v2 = ((const unsigned*)(xin + (size_t)e.z * DD))[lane];
    unsigned v3 = ((const unsigned*)(xin + (size_t)e.w * DD))[lane];
    // pad entries are src=0 (csr zero-filled): row 0 stays cached, mask cheap
    v1 = (j + 1 < cnt) ? v1 : 0u;
    v2 = (j + 2 < cnt) ? v2 : 0u;
    v3 = (j + 3 < cnt) ? v3 : 0u;
    ax0 += bflo(v0); ay0 += bfhi(v0);
    ax1 += bflo(v1); ay1 += bfhi(v1);
    ax2 += bflo(v2); ay2 += bfhi(v2);
    ax3 += bflo(v3); ay3 += bfhi(v3);
  }
  const float s = dinv[n] * dinv[n];
  const float rx = ((ax0 + ax1) + (ax2 + ax3)) * s;
  const float ry = ((ay0 + ay1) + (ay2 + ay3)) * s;
  orow[lane] = ((unsigned)f2bf(ry) << 16) | (unsigned)f2bf(rx);
}

__global__ __launch_bounds__(256) void k_agg(const int* __restrict__ rowstart,
                                             const int* __restrict__ deg,
                                             const int* __restrict__ csr,
                                             const float* __restrict__ dinv,
                                             const unsigned short* __restrict__ xin,
                                             unsigned short* __restrict__ xout) {
  const int lane = threadIdx.x & 63;
  const int wid = (blockIdx.x * blockDim.x + threadIdx.x) >> 6;
  const int nw = (gridDim.x * blockDim.x) >> 6;
  for (int n = wid; n < NN; n += nw)
    agg_row(n, lane, rowstart, deg, csr, dinv, xin, xout);
}

__global__ __launch_bounds__(256) void k_agg_list(const int* __restrict__ rowstart,
                                                  const int* __restrict__ deg,
                                                  const int* __restrict__ csr,
                                                  const float* __restrict__ dinv,
                                                  const unsigned short* __restrict__ xin,
                                                  unsigned short* __restrict__ xout,
                                                  const int* __restrict__ list,
                                                  const int* __restrict__ lcnt) {
  const int lane = threadIdx.x & 63;
  const int wid = (blockIdx.x * blockDim.x + threadIdx.x) >> 6;
  const int nw = (gridDim.x * blockDim.x) >> 6;
  const int cl = *lcnt;
  for (int i = wid; i < cl; i += nw)
    agg_row(list[i], lane, rowstart, deg, csr, dinv, xin, xout);
}

// ---- gather + l2-normalize selected bf16 rows -> bf16 A-matrix slice ----
// normalize is scale-invariant, so reading u = dinv*x gives the same z.
__global__ __launch_bounds__(256) void k_gnorm(const int* __restrict__ sl,
                                               const int* __restrict__ rl,
                                               const unsigned short* __restrict__ xin,
                                               unsigned short* __restrict__ Abf,
                                               int colbase) {
  const int lane = threadIdx.x & 63;
  const int row = blockIdx.x * 4 + (threadIdx.x >> 6);
  if (row >= MROWS) return;
  const int node = (row < SEL) ? sl[row] : rl[row - SEL];
  const unsigned v = ((const unsigned*)(xin + (size_t)node * DD))[lane];
  const float x0 = bflo(v), x1 = bfhi(v);
  float ss = fmaf(x0, x0, x1 * x1);
  #pragma unroll
  for (int m = 32; m >= 1; m >>= 1) ss += __shfl_xor(ss, m);
  const float sc = 1.0f / fmaxf(sqrtf(ss), 1e-12f);
  const unsigned short b0 = f2bf(x0 * sc), b1 = f2bf(x1 * sc);
  const unsigned pack = ((unsigned)b1 << 16) | (unsigned)b0;
  *(unsigned*)(Abf + (size_t)row * MD + colbase + lane * 2) = pack;
}

// ---- W f32 -> bf16 ----
__global__ void k_conv(const float* __restrict__ in, unsigned short* __restrict__ out,
                       int n4) {
  int i = blockIdx.x * blockDim.x + threadIdx.x;
  if (i >= n4) return;
  float4 v = ((const float4*)in)[i];
  ushort4 o;
  o.x = f2bf(v.x); o.y = f2bf(v.y); o.z = f2bf(v.z); o.w = f2bf(v.w);
  ((ushort4*)out)[i] = o;
}

// ---- emb f32 -> u0 bf16 = dinv[n] * emb[n] ----
__global__ void k_conv_emb(const float* __restrict__ emb, const float* __restrict__ dinv,
                           unsigned short* __restrict__ out) {
  int i = blockIdx.x * blockDim.x + threadIdx.x;
  if (i >= NN * DD / 4) return;
  const float d = dinv[i >> 5];  // 32 float4s per 128-wide row
  float4 v = ((const float4*)emb)[i];
  ushort4 o;
  o.x = f2bf(v.x * d); o.y = f2bf(v.y * d); o.z = f2bf(v.z * d); o.w = f2bf(v.w * d);
  ((ushort4*)out)[i] = o;
}

// ---- MFMA GEMM: out[i][j] = sum_k A[i][k]*W[j][k] + bias[j] ----
__global__ __launch_bounds__(256) void k_gemm(const unsigned short* __restrict__ A,
                                              const unsigned short* __restrict__ B,
                                              const float* __restrict__ bias,
                                              float* __restrict__ out) {
  __shared__ unsigned short As[128][40];  // +8 pad breaks bank conflicts
  __shared__ unsigned short Bs[128][40];
  const int t = threadIdx.x;
  const int mt = blockIdx.x >> 2, nt = blockIdx.x & 3;
  const int i0 = mt * 128, j0 = nt * 128;
  const int lane = t & 63, wid = t >> 6;
  const int wr = wid >> 1, wc = wid & 1;    // 2x2 waves, 64x64 each
  const int fr = lane & 15, kg = lane >> 4; // fragment row/col, k-group
  f32x4 acc[4][4] = {};
  for (int k0 = 0; k0 < MD; k0 += 32) {
    #pragma unroll
    for (int rep = 0; rep < 2; ++rep) {
      int id = t + rep * 256;
      int row = id >> 2, seg = id & 3;  // 128 rows x 4 segs of 8 bf16
      float4 va = *(const float4*)(A + (size_t)(i0 + row) * MD + k0 + seg * 8);
      *(float4*)(&As[row][seg * 8]) = va;
      float4 vb = *(const float4*)(B + (size_t)(j0 + row) * MD + k0 + seg * 8);
      *(float4*)(&Bs[row][seg * 8]) = vb;
    }
    __syncthreads();
    bf16x8 af[4], bfr[4];
    #pragma unroll
    for (int m = 0; m < 4; ++m)
      af[m] = *(const bf16x8*)(&As[wr * 64 + m * 16 + fr][kg * 8]);
    #pragma unroll
    for (int n = 0; n < 4; ++n)
      bfr[n] = *(const bf16x8*)(&Bs[wc * 64 + n * 16 + fr][kg * 8]);
    #pragma unroll
    for (int m = 0; m < 4; ++m)
      #pragma unroll
      for (int n = 0; n < 4; ++n)
        acc[m][n] = __builtin_amdgcn_mfma_f32_16x16x32_bf16(af[m], bfr[n], acc[m][n], 0, 0, 0);
    __syncthreads();
  }
  #pragma unroll
  for (int n = 0; n < 4; ++n) {
    int col = j0 + wc * 64 + n * 16 + fr;
    float bv = bias[col];
    #pragma unroll
    for (int m = 0; m < 4; ++m) {
      int r0 = i0 + wr * 64 + m * 16 + kg * 4;
      #pragma unroll
      for (int r = 0; r < 4; ++r)
        out[(size_t)(r0 + r) * MD + col] = acc[m][n][r] + bv;
    }
  }
}

extern "C" void kernel_launch(void* const* d_in, const int* in_sizes, int n_in,
                              void* d_out, int out_size, void* d_ws, size_t ws_size,
                              hipStream_t stream) {
  const float* emb = (const float*)d_in[0];
  const int* ei = (const int*)d_in[1];
  const int* esrc = ei;                     // edge_index[0]
  const int* edst = ei + NE;                // edge_index[1]
  const int* send = (const int*)d_in[2];
  const int* recv = (const int*)d_in[3];
  const float* W = (const float*)d_in[4];
  const float* bias = (const float*)d_in[5];
  float* out = (float*)d_out;

  char* ws = (char*)d_ws;
  size_t off = 0;
  auto take = [&](size_t b) {
    char* p = ws + off;
    off = (off + b + 1023) & ~(size_t)1023;
    return p;
  };
  const size_t CSRN = (size_t)NE + 4 * (size_t)NN;  // padded CSR capacity
  int* degI = (int*)take((size_t)NN * 4);
  float* dinv = (float*)take((size_t)NN * 4);
  int* rowstart = (int*)take((size_t)NN * 4);
  int* cursor = (int*)take((size_t)NN * 4);
  int* mark = (int*)take((size_t)NN * 4);
  int* list = (int*)take((size_t)MROWS * 4);
  int* lcnt = (int*)take(4);
  int* part = (int*)take(256 * 4);
  int* csr = (int*)take(CSRN * 4);
  unsigned short* x0 = (unsigned short*)take((size_t)NN * DD * 2);
  unsigned short* x1 = (unsigned short*)take((size_t)NN * DD * 2);
  unsigned short* x2 = (unsigned short*)take((size_t)NN * DD * 2);
  unsigned short* Abf = (unsigned short*)take((size_t)MROWS * MD * 2);
  unsigned short* Wbf = (unsigned short*)take((size_t)MD * MD * 2);
  (void)ws_size; (void)in_sizes; (void)n_in; (void)out_size;

  hipMemsetAsync(degI, 0, (size_t)NN * 4, stream);
  hipMemsetAsync(cursor, 0, (size_t)NN * 4, stream);
  hipMemsetAsync(mark, 0, (size_t)NN * 4, stream);
  hipMemsetAsync(lcnt, 0, 4, stream);
  hipMemsetAsync(csr, 0, CSRN * 4, stream);  // pad entries -> src 0

  k_deg<<<(NE + 255) / 256, 256, 0, stream>>>(edst, degI);
  k_dinv<<<(NN + 255) / 256, 256, 0, stream>>>(degI, dinv);
  const int NB = (NN + 1023) / 1024;
  k_scan1<<<NB, 1024, 0, stream>>>(degI, rowstart, part);
  k_scan2<<<1, 256, 0, stream>>>(part, NB);
  k_scan3<<<(NN + 255) / 256, 256, 0, stream>>>(rowstart, part);
  k_fill<<<2048, 256, 0, stream>>>(esrc, edst, rowstart, cursor, csr);
  k_mark<<<(2 * SEL + 255) / 256, 256, 0, stream>>>(send, recv, mark);
  k_compact<<<(NN + 255) / 256, 256, 0, stream>>>(mark, list, lcnt);
  k_conv<<<(MD * MD / 4 + 255) / 256, 256, 0, stream>>>(W, Wbf, MD * MD / 4);
  k_conv_emb<<<(NN * DD / 4 + 255) / 256, 256, 0, stream>>>(emb, dinv, x0);

  // z1 slice from u0; 2 full layers; masked final layer (reuses x0)
  k_gnorm<<<MROWS / 4, 256, 0, stream>>>(send, recv, x0, Abf, 0);
  k_agg<<<2048, 256, 0, stream>>>(rowstart, degI, csr, dinv, x0, x1);
  k_gnorm<<<MROWS / 4, 256, 0, stream>>>(send, recv, x1, Abf, 128);
  k_agg<<<2048, 256, 0, stream>>>(rowstart, degI, csr, dinv, x1, x2);
  k_gnorm<<<MROWS / 4, 256, 0, stream>>>(send, recv, x2, Abf, 256);
  k_agg_list<<<1024, 256, 0, stream>>>(rowstart, degI, csr, dinv, x2, x0, list, lcnt);
  k_gnorm<<<MROWS / 4, 256, 0, stream>>>(send, recv, x0, Abf, 384);

  k_gemm<<<(MROWS / 128) * (MD / 128), 256, 0, stream>>>(Abf, Wbf, bias, out);
}

// Round 5
// 366.335 us; speedup vs baseline: 1.2274x; 1.2039x over previous
//
#include <hip/hip_runtime.h>

#define NN 100000      // nodes
#define NE 1600000     // edges
#define DD 128         // input dim (elements per row)
#define MD 512         // mlp dim = 128*4
#define SEL 16384      // senders count
#define MROWS 32768    // senders + receivers rows
#define NBKT 196       // buckets of 512 nodes (100000>>9 = 195)
#define TILE 4096      // edges per k_binA block
#define SEGCAP 12288   // max padded CSR slots per bucket (mean 8192+pad, 28 sigma)

typedef __attribute__((ext_vector_type(8))) short bf16x8;
typedef __attribute__((ext_vector_type(4))) float f32x4;

__device__ __forceinline__ unsigned short f2bf(float f) {
  unsigned u = __float_as_uint(f);
  u += 0x7fff + ((u >> 16) & 1);   // round-to-nearest-even
  return (unsigned short)(u >> 16);
}
__device__ __forceinline__ float bflo(unsigned v) { return __uint_as_float(v << 16); }
__device__ __forceinline__ float bfhi(unsigned v) { return __uint_as_float(v & 0xffff0000u); }

// ---- bucket histogram over dst (one streaming pass) ----
__global__ __launch_bounds__(256) void k_histo(const int* __restrict__ dst,
                                               int* __restrict__ bcnt) {
  __shared__ int h[NBKT];
  for (int i = threadIdx.x; i < NBKT; i += 256) h[i] = 0;
  __syncthreads();
  for (long e = blockIdx.x * 256L + threadIdx.x; e < NE; e += (long)gridDim.x * 256)
    atomicAdd(&h[dst[e] >> 9], 1);
  __syncthreads();
  for (int i = threadIdx.x; i < NBKT; i += 256)
    if (h[i]) atomicAdd(&bcnt[i], h[i]);
}

// ---- exclusive scan of bucket counts -> bstart + live cursor ----
__global__ __launch_bounds__(256) void k_bscan(const int* __restrict__ bcnt,
                                               int* __restrict__ gcursor,
                                               int* __restrict__ bstart) {
  __shared__ int sm[256];
  int tid = threadIdx.x;
  int v = (tid < NBKT) ? bcnt[tid] : 0;
  sm[tid] = v;
  __syncthreads();
  for (int o = 1; o < 256; o <<= 1) {
    int t = (tid >= o) ? sm[tid - o] : 0;
    __syncthreads();
    sm[tid] += t;
    __syncthreads();
  }
  if (tid < NBKT) {
    int ex = sm[tid] - v;
    gcursor[tid] = ex;
    bstart[tid] = ex;
  }
}

// ---- bin edges by bucket: ebuf[slot] = src<<9 | (dst&511), bucket-contig ----
__global__ __launch_bounds__(256) void k_binA(const int* __restrict__ src,
                                              const int* __restrict__ dst,
                                              int* __restrict__ gcursor,
                                              unsigned* __restrict__ ebuf) {
  __shared__ int hist[NBKT];
  __shared__ int base[NBKT];
  __shared__ int cnt2[NBKT];
  const int tid = threadIdx.x;
  const long e0 = (long)blockIdx.x * TILE;
  for (int i = tid; i < NBKT; i += 256) { hist[i] = 0; cnt2[i] = 0; }
  __syncthreads();
  unsigned pk[16]; int bk[16];
  #pragma unroll
  for (int k = 0; k < 16; ++k) {
    const long e = e0 + k * 256 + tid;
    bk[k] = -1;
    if (e < NE) {
      const int d = dst[e], s = src[e];
      bk[k] = d >> 9;
      pk[k] = ((unsigned)s << 9) | (unsigned)(d & 511);
      atomicAdd(&hist[bk[k]], 1);
    }
  }
  __syncthreads();
  for (int i = tid; i < NBKT; i += 256)
    base[i] = atomicAdd(&gcursor[i], hist[i]);
  __syncthreads();
  #pragma unroll
  for (int k = 0; k < 16; ++k) {
    if (bk[k] >= 0) {
      const int lp = atomicAdd(&cnt2[bk[k]], 1);
      ebuf[base[bk[k]] + lp] = pk[k];
    }
  }
}

// ---- per-bucket degree from binned edges (contiguous deg writes) ----
__global__ __launch_bounds__(256) void k_degB(const unsigned* __restrict__ ebuf,
                                              const int* __restrict__ bstart,
                                              const int* __restrict__ bcnt,
                                              int* __restrict__ deg) {
  __shared__ int ld[512];
  const int b = blockIdx.x;
  const int n0 = b << 9;
  const int nn = min(512, NN - n0);
  for (int i = threadIdx.x; i < 512; i += 256) ld[i] = 0;
  __syncthreads();
  const int s0 = bstart[b], c = bcnt[b];
  for (int i = threadIdx.x; i < c; i += 256)
    atomicAdd(&ld[ebuf[s0 + i] & 511], 1);
  __syncthreads();
  for (int i = threadIdx.x; i < nn; i += 256) deg[n0 + i] = ld[i];
}

__global__ void k_dinv(const int* __restrict__ deg, float* __restrict__ dinv) {
  int n = blockIdx.x * blockDim.x + threadIdx.x;
  if (n < NN) dinv[n] = rsqrtf(fmaxf((float)deg[n], 1.0f));
}

// ---- exclusive scan of PADDED degree -> rowstart (3-kernel) ----
__global__ __launch_bounds__(1024) void k_scan1(const int* __restrict__ deg,
                                                int* __restrict__ excl,
                                                int* __restrict__ part) {
  __shared__ int sm[1024];
  int tid = threadIdx.x;
  int i = blockIdx.x * 1024 + tid;
  int v = (i < NN) ? ((deg[i] + 3) & ~3) : 0;
  sm[tid] = v;
  __syncthreads();
  for (int o = 1; o < 1024; o <<= 1) {
    int t = (tid >= o) ? sm[tid - o] : 0;
    __syncthreads();
    sm[tid] += t;
    __syncthreads();
  }
  if (i < NN) excl[i] = sm[tid] - v;
  if (tid == 1023) part[blockIdx.x] = sm[1023];
}

__global__ __launch_bounds__(256) void k_scan2(int* __restrict__ part, int nb) {
  __shared__ int sm[256];
  int tid = threadIdx.x;
  int v = (tid < nb) ? part[tid] : 0;
  sm[tid] = v;
  __syncthreads();
  for (int o = 1; o < 256; o <<= 1) {
    int t = (tid >= o) ? sm[tid - o] : 0;
    __syncthreads();
    sm[tid] += t;
    __syncthreads();
  }
  if (tid < nb) part[tid] = sm[tid] - v;
}

__global__ void k_scan3(int* __restrict__ excl, const int* __restrict__ part) {
  int i = blockIdx.x * blockDim.x + threadIdx.x;
  if (i < NN) excl[i] += part[i >> 10];
}

// ---- per-bucket LDS scatter into padded CSR layout, coalesced out ----
__global__ __launch_bounds__(256) void k_binB(const unsigned* __restrict__ ebuf,
                                              const int* __restrict__ bstart,
                                              const int* __restrict__ bcnt,
                                              const int* __restrict__ rowstart,
                                              const int* __restrict__ deg,
                                              int* __restrict__ csr) {
  __shared__ int seg[SEGCAP];
  __shared__ int rs[512];
  __shared__ int cnt[512];
  const int b = blockIdx.x;
  const int n0 = b << 9;
  const int nn = min(512, NN - n0);
  const int seg0 = rowstart[n0];
  const int nlast = n0 + nn - 1;
  const int seglen = rowstart[nlast] + ((deg[nlast] + 3) & ~3) - seg0;
  for (int i = threadIdx.x; i < nn; i += 256) {
    rs[i] = rowstart[n0 + i] - seg0;
    cnt[i] = 0;
  }
  for (int i = threadIdx.x; i < seglen; i += 256) seg[i] = 0;
  __syncthreads();
  const int s0 = bstart[b], c = bcnt[b];
  for (int i = threadIdx.x; i < c; i += 256) {
    const unsigned e = ebuf[s0 + i];
    const int dl = e & 511;
    const int pos = rs[dl] + atomicAdd(&cnt[dl], 1);
    if (pos < SEGCAP) seg[pos] = (int)(e >> 9);
  }
  __syncthreads();
  for (int i = threadIdx.x; i < seglen; i += 256) csr[seg0 + i] = seg[i];
}

// ---- mark + compact the nodes needed by the final layer ----
__global__ void k_mark(const int* __restrict__ sl, const int* __restrict__ rl,
                       int* __restrict__ mark) {
  int i = blockIdx.x * blockDim.x + threadIdx.x;
  if (i < SEL) mark[sl[i]] = 1;
  else if (i < 2 * SEL) mark[rl[i - SEL]] = 1;
}

__global__ void k_compact(const int* __restrict__ mark, int* __restrict__ list,
                          int* __restrict__ cnt) {
  int n = blockIdx.x * blockDim.x + threadIdx.x;
  if (n < NN && mark[n]) {
    int p = atomicAdd(cnt, 1);
    list[p] = n;
  }
}

// ---- per-node aggregation of u = dinv*x: pure sum, then dinv^2 scale ----
__device__ __forceinline__ void agg_row(int n, int lane,
                                        const int* __restrict__ rowstart,
                                        const int* __restrict__ deg,
                                        const int* __restrict__ csr,
                                        const float* __restrict__ dinv,
                                        const unsigned short* __restrict__ xin,
                                        unsigned short* __restrict__ xout) {
  const int start = rowstart[n];
  const int cnt = deg[n];
  unsigned* orow = (unsigned*)(xout + (size_t)n * DD);
  if (cnt == 0) { orow[lane] = 0u; return; }
  float ax0 = 0.f, ay0 = 0.f, ax1 = 0.f, ay1 = 0.f;
  float ax2 = 0.f, ay2 = 0.f, ax3 = 0.f, ay3 = 0.f;
  for (int j = 0; j < cnt; j += 4) {
    const int4 e = *(const int4*)(csr + start + j);  // 16B-aligned (padded rows)
    unsigned v0 = ((const unsigned*)(xin + (size_t)e.x * DD))[lane];
    unsigned v1 = ((const unsigned*)(xin + (size_t)e.y * DD))[lane];
    unsigned v2 = ((const unsigned*)(xin + (size_t)e.z * DD))[lane];
    unsigned v3 = ((const unsigned*)(xin + (size_t)e.w * DD))[lane];
    // pad entries are src=0: row 0 stays cached, mask cheap
    v1 = (j + 1 < cnt) ? v1 : 0u;
    v2 = (j + 2 < cnt) ? v2 : 0u;
    v3 = (j + 3 < cnt) ? v3 : 0u;
    ax0 += bflo(v0); ay0 += bfhi(v0);
    ax1 += bflo(v1); ay1 += bfhi(v1);
    ax2 += bflo(v2); ay2 += bfhi(v2);
    ax3 += bflo(v3); ay3 += bfhi(v3);
  }
  const float s = dinv[n] * dinv[n];
  const float rx = ((ax0 + ax1) + (ax2 + ax3)) * s;
  const float ry = ((ay0 + ay1) + (ay2 + ay3)) * s;
  orow[lane] = ((unsigned)f2bf(ry) << 16) | (unsigned)f2bf(rx);
}

__global__ __launch_bounds__(256) void k_agg(const int* __restrict__ rowstart,
                                             const int* __restrict__ deg,
                                             const int* __restrict__ csr,
                                             const float* __restrict__ dinv,
                                             const unsigned short* __restrict__ xin,
                                             unsigned short* __restrict__ xout) {
  const int lane = threadIdx.x & 63;
  const int wid = (blockIdx.x * blockDim.x + threadIdx.x) >> 6;
  const int nw = (gridDim.x * blockDim.x) >> 6;
  for (int n = wid; n < NN; n += nw)
    agg_row(n, lane, rowstart, deg, csr, dinv, xin, xout);
}

__global__ __launch_bounds__(256) void k_agg_list(const int* __restrict__ rowstart,
                                                  const int* __restrict__ deg,
                                                  const int* __restrict__ csr,
                                                  const float* __restrict__ dinv,
                                                  const unsigned short* __restrict__ xin,
                                                  unsigned short* __restrict__ xout,
                                                  const int* __restrict__ list,
                                                  const int* __restrict__ lcnt) {
  const int lane = threadIdx.x & 63;
  const int wid = (blockIdx.x * blockDim.x + threadIdx.x) >> 6;
  const int nw = (gridDim.x * blockDim.x) >> 6;
  const int cl = *lcnt;
  for (int i = wid; i < cl; i += nw)
    agg_row(list[i], lane, rowstart, deg, csr, dinv, xin, xout);
}

// ---- gather + l2-normalize selected bf16 rows -> bf16 A-matrix slice ----
__global__ __launch_bounds__(256) void k_gnorm(const int* __restrict__ sl,
                                               const int* __restrict__ rl,
                                               const unsigned short* __restrict__ xin,
                                               unsigned short* __restrict__ Abf,
                                               int colbase) {
  const int lane = threadIdx.x & 63;
  const int row = blockIdx.x * 4 + (threadIdx.x >> 6);
  if (row >= MROWS) return;
  const int node = (row < SEL) ? sl[row] : rl[row - SEL];
  const unsigned v = ((const unsigned*)(xin + (size_t)node * DD))[lane];
  const float x0 = bflo(v), x1 = bfhi(v);
  float ss = fmaf(x0, x0, x1 * x1);
  #pragma unroll
  for (int m = 32; m >= 1; m >>= 1) ss += __shfl_xor(ss, m);
  const float sc = 1.0f / fmaxf(sqrtf(ss), 1e-12f);
  const unsigned short b0 = f2bf(x0 * sc), b1 = f2bf(x1 * sc);
  const unsigned pack = ((unsigned)b1 << 16) | (unsigned)b0;
  *(unsigned*)(Abf + (size_t)row * MD + colbase + lane * 2) = pack;
}

// ---- W f32 -> bf16 ----
__global__ void k_conv(const float* __restrict__ in, unsigned short* __restrict__ out,
                       int n4) {
  int i = blockIdx.x * blockDim.x + threadIdx.x;
  if (i >= n4) return;
  float4 v = ((const float4*)in)[i];
  ushort4 o;
  o.x = f2bf(v.x); o.y = f2bf(v.y); o.z = f2bf(v.z); o.w = f2bf(v.w);
  ((ushort4*)out)[i] = o;
}

// ---- emb f32 -> u0 bf16 = dinv[n] * emb[n] ----
__global__ void k_conv_emb(const float* __restrict__ emb, const float* __restrict__ dinv,
                           unsigned short* __restrict__ out) {
  int i = blockIdx.x * blockDim.x + threadIdx.x;
  if (i >= NN * DD / 4) return;
  const float d = dinv[i >> 5];  // 32 float4s per 128-wide row
  float4 v = ((const float4*)emb)[i];
  ushort4 o;
  o.x = f2bf(v.x * d); o.y = f2bf(v.y * d); o.z = f2bf(v.z * d); o.w = f2bf(v.w * d);
  ((ushort4*)out)[i] = o;
}

// ---- MFMA GEMM: out[i][j] = sum_k A[i][k]*W[j][k] + bias[j] ----
__global__ __launch_bounds__(256) void k_gemm(const unsigned short* __restrict__ A,
                                              const unsigned short* __restrict__ B,
                                              const float* __restrict__ bias,
                                              float* __restrict__ out) {
  __shared__ unsigned short As[128][40];  // +8 pad breaks bank conflicts
  __shared__ unsigned short Bs[128][40];
  const int t = threadIdx.x;
  const int mt = blockIdx.x >> 2, nt = blockIdx.x & 3;
  const int i0 = mt * 128, j0 = nt * 128;
  const int lane = t & 63, wid = t >> 6;
  const int wr = wid >> 1, wc = wid & 1;    // 2x2 waves, 64x64 each
  const int fr = lane & 15, kg = lane >> 4; // fragment row/col, k-group
  f32x4 acc[4][4] = {};
  for (int k0 = 0; k0 < MD; k0 += 32) {
    #pragma unroll
    for (int rep = 0; rep < 2; ++rep) {
      int id = t + rep * 256;
      int row = id >> 2, seg = id & 3;  // 128 rows x 4 segs of 8 bf16
      float4 va = *(const float4*)(A + (size_t)(i0 + row) * MD + k0 + seg * 8);
      *(float4*)(&As[row][seg * 8]) = va;
      float4 vb = *(const float4*)(B + (size_t)(j0 + row) * MD + k0 + seg * 8);
      *(float4*)(&Bs[row][seg * 8]) = vb;
    }
    __syncthreads();
    bf16x8 af[4], bfr[4];
    #pragma unroll
    for (int m = 0; m < 4; ++m)
      af[m] = *(const bf16x8*)(&As[wr * 64 + m * 16 + fr][kg * 8]);
    #pragma unroll
    for (int n = 0; n < 4; ++n)
      bfr[n] = *(const bf16x8*)(&Bs[wc * 64 + n * 16 + fr][kg * 8]);
    #pragma unroll
    for (int m = 0; m < 4; ++m)
      #pragma unroll
      for (int n = 0; n < 4; ++n)
        acc[m][n] = __builtin_amdgcn_mfma_f32_16x16x32_bf16(af[m], bfr[n], acc[m][n], 0, 0, 0);
    __syncthreads();
  }
  #pragma unroll
  for (int n = 0; n < 4; ++n) {
    int col = j0 + wc * 64 + n * 16 + fr;
    float bv = bias[col];
    #pragma unroll
    for (int m = 0; m < 4; ++m) {
      int r0 = i0 + wr * 64 + m * 16 + kg * 4;
      #pragma unroll
      for (int r = 0; r < 4; ++r)
        out[(size_t)(r0 + r) * MD + col] = acc[m][n][r] + bv;
    }
  }
}

extern "C" void kernel_launch(void* const* d_in, const int* in_sizes, int n_in,
                              void* d_out, int out_size, void* d_ws, size_t ws_size,
                              hipStream_t stream) {
  const float* emb = (const float*)d_in[0];
  const int* ei = (const int*)d_in[1];
  const int* esrc = ei;                     // edge_index[0]
  const int* edst = ei + NE;                // edge_index[1]
  const int* send = (const int*)d_in[2];
  const int* recv = (const int*)d_in[3];
  const float* W = (const float*)d_in[4];
  const float* bias = (const float*)d_in[5];
  float* out = (float*)d_out;

  char* ws = (char*)d_ws;
  size_t off = 0;
  auto take = [&](size_t b) {
    char* p = ws + off;
    off = (off + b + 1023) & ~(size_t)1023;
    return p;
  };
  const size_t CSRN = (size_t)NE + 4 * (size_t)NN;  // padded CSR capacity
  int* degI = (int*)take((size_t)NN * 4);
  float* dinv = (float*)take((size_t)NN * 4);
  int* rowstart = (int*)take((size_t)NN * 4);
  int* bcnt = (int*)take(NBKT * 4);
  int* bstart = (int*)take(NBKT * 4);
  int* gcursor = (int*)take(NBKT * 4);
  int* mark = (int*)take((size_t)NN * 4);
  int* list = (int*)take((size_t)MROWS * 4);
  int* lcnt = (int*)take(4);
  int* part = (int*)take(256 * 4);
  unsigned* ebuf = (unsigned*)take((size_t)NE * 4);
  int* csr = (int*)take(CSRN * 4);
  unsigned short* x0 = (unsigned short*)take((size_t)NN * DD * 2);
  unsigned short* x1 = (unsigned short*)take((size_t)NN * DD * 2);
  unsigned short* x2 = (unsigned short*)take((size_t)NN * DD * 2);
  unsigned short* Abf = (unsigned short*)take((size_t)MROWS * MD * 2);
  unsigned short* Wbf = (unsigned short*)take((size_t)MD * MD * 2);
  (void)ws_size; (void)in_sizes; (void)n_in; (void)out_size;

  hipMemsetAsync(bcnt, 0, NBKT * 4, stream);
  hipMemsetAsync(mark, 0, (size_t)NN * 4, stream);
  hipMemsetAsync(lcnt, 0, 4, stream);

  // ---- CSR build: 2-level counting sort, all streaming traffic ----
  k_histo<<<1024, 256, 0, stream>>>(edst, bcnt);
  k_bscan<<<1, 256, 0, stream>>>(bcnt, gcursor, bstart);
  k_binA<<<(NE + TILE - 1) / TILE, 256, 0, stream>>>(esrc, edst, gcursor, ebuf);
  k_degB<<<NBKT, 256, 0, stream>>>(ebuf, bstart, bcnt, degI);
  k_dinv<<<(NN + 255) / 256, 256, 0, stream>>>(degI, dinv);
  const int NB = (NN + 1023) / 1024;
  k_scan1<<<NB, 1024, 0, stream>>>(degI, rowstart, part);
  k_scan2<<<1, 256, 0, stream>>>(part, NB);
  k_scan3<<<(NN + 255) / 256, 256, 0, stream>>>(rowstart, part);
  k_binB<<<NBKT, 256, 0, stream>>>(ebuf, bstart, bcnt, rowstart, degI, csr);

  k_mark<<<(2 * SEL + 255) / 256, 256, 0, stream>>>(send, recv, mark);
  k_compact<<<(NN + 255) / 256, 256, 0, stream>>>(mark, list, lcnt);
  k_conv<<<(MD * MD / 4 + 255) / 256, 256, 0, stream>>>(W, Wbf, MD * MD / 4);
  k_conv_emb<<<(NN * DD / 4 + 255) / 256, 256, 0, stream>>>(emb, dinv, x0);

  // z1 slice from u0; 2 full layers; masked final layer (reuses x0)
  k_gnorm<<<MROWS / 4, 256, 0, stream>>>(send, recv, x0, Abf, 0);
  k_agg<<<2048, 256, 0, stream>>>(rowstart, degI, csr, dinv, x0, x1);
  k_gnorm<<<MROWS / 4, 256, 0, stream>>>(send, recv, x1, Abf, 128);
  k_agg<<<2048, 256, 0, stream>>>(rowstart, degI, csr, dinv, x1, x2);
  k_gnorm<<<MROWS / 4, 256, 0, stream>>>(send, recv, x2, Abf, 256);
  k_agg_list<<<1024, 256, 0, stream>>>(rowstart, degI, csr, dinv, x2, x0, list, lcnt);
  k_gnorm<<<MROWS / 4, 256, 0, stream>>>(send, recv, x0, Abf, 384);

  k_gemm<<<(MROWS / 128) * (MD / 128), 256, 0, stream>>>(Abf, Wbf, bias, out);
}